// Round 15
// baseline (210.644 us; speedup 1.0000x reference)
//
#include <hip/hip_runtime.h>
#include <hip/hip_cooperative_groups.h>

namespace cg = cooperative_groups;

#define LOG2E 1.4426950408889634f

// Problem constants
constexpr int Bb = 4, LQ = 512, LK = 512, QS = 512, H = 256, DV = 512;
constexpr int M = 2048;   // B*LQ

// Workspace byte offsets
constexpr size_t OFF_EQT = 0;            // [256][2048] f32 (2 MiB) exp2-domain q proj
constexpr size_t OFF_EKT = 2u << 20;     // [256][2048] f32 (2 MiB)
constexpr size_t OFF_PQ  = 4u << 20;     // [4][512][512] bf16 (2 MiB) P numerators
constexpr size_t OFF_ROW = 6u << 20;     // [8][2048] f32 rowsum partials

using bf16x8 = __attribute__((ext_vector_type(8))) short;
using f32x4v = __attribute__((ext_vector_type(4))) float;

__device__ inline unsigned short f2bf(float x) {
    unsigned int u = __float_as_uint(x);
    u += 0x7FFFu + ((u >> 16) & 1u);      // round-to-nearest-even
    return (unsigned short)(u >> 16);
}
__device__ inline unsigned int pk2(float lo, float hi) {
    return (unsigned int)f2bf(lo) | ((unsigned int)f2bf(hi) << 16);
}

// ---------------------------------------------------------------------------
// Single cooperative kernel, 3 phases, grid.sync() between them.
// All phases use exactly 256 blocks x 256 threads (1 block/CU co-resident).
// Phase bodies identical to R14's proj_mfma / score_kernel / av_mfma.
// R15 change: fusion only — removes 2 kernel launches + teardowns (~4-5 us
// dispatch overhead each was the largest unaccounted term in the budget).
// ---------------------------------------------------------------------------
__global__ __launch_bounds__(256, 1) void fused_kernel(
    const float* __restrict__ query, const float* __restrict__ key,
    const float* __restrict__ value,
    const float* __restrict__ wq, const float* __restrict__ wk,
    const float* __restrict__ bq, const float* __restrict__ bk,
    const float* __restrict__ wvp,
    char* __restrict__ ws, float* __restrict__ out_, float scale)
{
    cg::grid_group grid = cg::this_grid();

    __shared__ __align__(16) char arena[52224];

    const int tid = threadIdx.x;
    const int bid = blockIdx.x;
    const int wid = tid >> 6, lane = tid & 63;
    const int ml = lane & 15, quad = lane >> 4;

    // ===================== Phase 1: proj (bf16 MFMA + exp2) ================
    {
        auto Als = (unsigned short (*)[136])(arena);            // 17408 B
        auto Wls = (unsigned short (*)[136])(arena + 17408);    // 17408 B
        auto Ot  = (float (*)[68])(arena + 34816);              // 17408 B

        const int z   = bid >> 7;          // 0: q-side, 1: k-side
        const int rem = bid & 127;
        const int mb  = (rem >> 2) * 64;   // 0..31 -> m block
        const int nb  = (rem & 3) * 64;    // 0..3  -> n block
        const float* A    = z ? key : query;   // [2048][512]
        const float* W    = z ? wk : wq;       // [256][512]
        const float* bias = z ? bk : bq;
        float* outp = (float*)(ws + (z ? OFF_EKT : OFF_EQT));   // [256][2048]

        f32x4v acc[4] = {{0,0,0,0},{0,0,0,0},{0,0,0,0},{0,0,0,0}};

        for (int kc = 0; kc < QS; kc += 128) {
            __syncthreads();
#pragma unroll
            for (int it = 0; it < 4; ++it) {
                int u = tid + it * 256;          // 0..1023 units of 8 elems
                int row = u >> 4, c8 = (u & 15) * 8;
                float4 a0 = *(const float4*)(A + (size_t)(mb + row) * 512 + kc + c8);
                float4 a1 = *(const float4*)(A + (size_t)(mb + row) * 512 + kc + c8 + 4);
                uint4 pa = { pk2(a0.x, a0.y), pk2(a0.z, a0.w), pk2(a1.x, a1.y), pk2(a1.z, a1.w) };
                *(uint4*)&Als[row][c8] = pa;
                float4 w0 = *(const float4*)(W + (size_t)(nb + row) * 512 + kc + c8);
                float4 w1 = *(const float4*)(W + (size_t)(nb + row) * 512 + kc + c8 + 4);
                uint4 pw = { pk2(w0.x, w0.y), pk2(w0.z, w0.w), pk2(w1.x, w1.y), pk2(w1.z, w1.w) };
                *(uint4*)&Wls[row][c8] = pw;
            }
            __syncthreads();
#pragma unroll
            for (int s = 0; s < 4; ++s) {
                int k = s * 32 + quad * 8;
                bf16x8 af = *(const bf16x8*)&Als[wid * 16 + ml][k];
#pragma unroll
                for (int nt = 0; nt < 4; ++nt) {
                    bf16x8 bfr = *(const bf16x8*)&Wls[nt * 16 + ml][k];
                    acc[nt] = __builtin_amdgcn_mfma_f32_16x16x32_bf16(af, bfr, acc[nt], 0, 0, 0);
                }
            }
        }
        __syncthreads();
#pragma unroll
        for (int nt = 0; nt < 4; ++nt)
#pragma unroll
            for (int r = 0; r < 4; ++r)
                Ot[nt * 16 + ml][wid * 16 + quad * 4 + r] = acc[nt][r];
        __syncthreads();
        {
            int r0 = tid >> 2;            // n-local 0..63
            int c0 = (tid & 3) * 16;      // m-local base
            float bs = bias[nb + r0];
#pragma unroll
            for (int g = 0; g < 4; ++g) {
                float4 v = *(const float4*)&Ot[r0][c0 + g * 4];
                float4 o;
                o.x = __builtin_amdgcn_exp2f(fminf(fmaxf(scale * (v.x + bs), -15.f), 15.f));
                o.y = __builtin_amdgcn_exp2f(fminf(fmaxf(scale * (v.y + bs), -15.f), 15.f));
                o.z = __builtin_amdgcn_exp2f(fminf(fmaxf(scale * (v.z + bs), -15.f), 15.f));
                o.w = __builtin_amdgcn_exp2f(fminf(fmaxf(scale * (v.w + bs), -15.f), 15.f));
                *(float4*)(outp + (size_t)(nb + r0) * 2048 + mb + c0 + g * 4) = o;
            }
        }
    }

    grid.sync();

    // ===================== Phase 2: score (quad-paired rcp) ================
    {
        const float* EqT = (const float*)(ws + OFF_EQT);   // [256][2048]
        const float* EkT = (const float*)(ws + OFF_EKT);
        unsigned short* Pq = (unsigned short*)(ws + OFF_PQ);  // [4][512][512] bf16
        float* rowpart = (float*)(ws + OFF_ROW);              // [8][2048]

        auto Qs   = (float (*)[64])(arena);                 // 16384 B
        auto Ks   = (float (*)[64])(arena + 16384);         // 16384 B
        float* Wv2 = (float*)(arena + 32768);               // 1024 B
        auto redS = (float (*)[64])(arena + 33792);         // 1024 B

        const int b   = bid >> 6;
        const int rem = bid & 63;
        const int qb  = (rem >> 3) * 64;
        const int kt  = rem & 7;
        const int kb  = kt * 64;
        const int tx = tid & 15;       // q frag: tx*4 + i
        const int ty = tid >> 4;       // k frag: ty*4 + j   (0..15)

        Wv2[tid] = wvp[tid] * (2.0f * LOG2E);   // blockDim == H == 256

        const int mq = b * LQ + qb;
        const int mk = b * LK + kb;
        const int sh = tid >> 4;       // staging row 0..15 (+16 steps)
        const int sm = (tid & 15) * 4;

        float acc[4][4] = {};

        for (int h0 = 0; h0 < H; h0 += 64) {
            __syncthreads();   // also covers the Wv2 write on the first pass
#pragma unroll
            for (int it = 0; it < 4; ++it) {
                int h = sh + 16 * it;
                *(float4*)&Qs[h][sm] = *(const float4*)(EqT + (size_t)(h0 + h) * M + mq + sm);
                *(float4*)&Ks[h][sm] = *(const float4*)(EkT + (size_t)(h0 + h) * M + mk + sm);
            }
            __syncthreads();
#pragma unroll 4
            for (int hh = 0; hh < 64; hh += 4) {
                float4 q1 = *(const float4*)&Qs[hh][tx * 4];
                float4 q2 = *(const float4*)&Qs[hh + 1][tx * 4];
                float4 q3 = *(const float4*)&Qs[hh + 2][tx * 4];
                float4 q4 = *(const float4*)&Qs[hh + 3][tx * 4];
                float4 k1 = *(const float4*)&Ks[hh][ty * 4];
                float4 k2 = *(const float4*)&Ks[hh + 1][ty * 4];
                float4 k3 = *(const float4*)&Ks[hh + 2][ty * 4];
                float4 k4 = *(const float4*)&Ks[hh + 3][ty * 4];
                float4 w4v = *(const float4*)&Wv2[h0 + hh];
                const float w1 = w4v.x, w2 = w4v.y, w3 = w4v.z, w4 = w4v.w;
                const float q1a[4] = {q1.x, q1.y, q1.z, q1.w};
                const float q2a[4] = {q2.x, q2.y, q2.z, q2.w};
                const float q3a[4] = {q3.x, q3.y, q3.z, q3.w};
                const float q4a[4] = {q4.x, q4.y, q4.z, q4.w};
                const float k1a[4] = {k1.x, k1.y, k1.z, k1.w};
                const float k2a[4] = {k2.x, k2.y, k2.z, k2.w};
                const float k3a[4] = {k3.x, k3.y, k3.z, k3.w};
                const float k4a[4] = {k4.x, k4.y, k4.z, k4.w};
#pragma unroll
                for (int i = 0; i < 4; ++i)
#pragma unroll
                    for (int j = 0; j < 4; ++j) {
                        float ta = fmaf(q1a[i], k1a[j], 1.0f);
                        float tb = fmaf(q2a[i], k2a[j], 1.0f);
                        float tc = fmaf(q3a[i], k3a[j], 1.0f);
                        float td = fmaf(q4a[i], k4a[j], 1.0f);
                        float t12 = ta * tb;
                        float t34 = tc * td;
                        float n12 = fmaf(w1, tb, w2 * ta);
                        float n34 = fmaf(w3, td, w4 * tc);
                        float num = fmaf(n12, t34, n34 * t12);
                        float den = t12 * t34;
                        acc[i][j] = fmaf(num, __builtin_amdgcn_rcpf(den), acc[i][j]);
                    }
            }
        }

        // Epilogue: P = exp2(-acc) -> bf16 Pq; row partials.
        float ps[4];
#pragma unroll
        for (int i = 0; i < 4; ++i) {
            int q = qb + tx * 4 + i;
            float p0 = __builtin_amdgcn_exp2f(-acc[i][0]);
            float p1 = __builtin_amdgcn_exp2f(-acc[i][1]);
            float p2 = __builtin_amdgcn_exp2f(-acc[i][2]);
            float p3 = __builtin_amdgcn_exp2f(-acc[i][3]);
            ps[i] = (p0 + p1) + (p2 + p3);
            uint2 o = { pk2(p0, p1), pk2(p2, p3) };
            *(uint2*)(Pq + ((size_t)(b * 512 + q) * 512 + kb + ty * 4)) = o;
        }
#pragma unroll
        for (int i = 0; i < 4; ++i) {
            ps[i] += __shfl_xor(ps[i], 16, 64);
            ps[i] += __shfl_xor(ps[i], 32, 64);
        }
        if (lane < 16) {
#pragma unroll
            for (int i = 0; i < 4; ++i) redS[wid][tx * 4 + i] = ps[i];
        }
        __syncthreads();
        if (tid < 64) {
            float s = (redS[0][tid] + redS[1][tid]) + (redS[2][tid] + redS[3][tid]);
            rowpart[(size_t)kt * 2048 + b * 512 + qb + tid] = s;
        }
    }

    grid.sync();

    // ===================== Phase 3: av (bf16 MFMA + normalize) =============
    {
        const unsigned short* Pq = (const unsigned short*)(ws + OFF_PQ);
        const float* rowpart = (const float*)(ws + OFF_ROW);

        auto Pls = (unsigned short (*)[136])(arena);            // 17408 B
        auto Vls = (unsigned short (*)[136])(arena + 17408);    // 17408 B

        const int b   = bid >> 6;
        const int rem = bid & 63;
        const int qb  = (rem >> 3) * 64;
        const int nb  = (rem & 7) * 64;
        const unsigned short* Pb = Pq + (size_t)b * 512 * 512;
        const float* Vb = value + (size_t)b * 512 * 512;

        f32x4v acc[4] = {{0,0,0,0},{0,0,0,0},{0,0,0,0},{0,0,0,0}};

        for (int kc = 0; kc < LK; kc += 128) {
            __syncthreads();
#pragma unroll
            for (int it = 0; it < 4; ++it) {
                int u = tid + it * 256;
                int row = u >> 4, c8 = (u & 15) * 8;
                *(uint4*)&Pls[row][c8] = *(const uint4*)(Pb + (size_t)(qb + row) * 512 + kc + c8);
            }
#pragma unroll
            for (int it = 0; it < 8; ++it) {
                int u = tid + it * 256;           // 2048 float4 units
                int k = u >> 4, c4 = (u & 15) * 4;
                float4 v4 = *(const float4*)(Vb + (size_t)(kc + k) * 512 + nb + c4);
                Vls[c4 + 0][k] = f2bf(v4.x);
                Vls[c4 + 1][k] = f2bf(v4.y);
                Vls[c4 + 2][k] = f2bf(v4.z);
                Vls[c4 + 3][k] = f2bf(v4.w);
            }
            __syncthreads();
#pragma unroll
            for (int s = 0; s < 4; ++s) {
                int k = s * 32 + quad * 8;
                bf16x8 af = *(const bf16x8*)&Pls[wid * 16 + ml][k];
#pragma unroll
                for (int nt = 0; nt < 4; ++nt) {
                    bf16x8 bfr = *(const bf16x8*)&Vls[nt * 16 + ml][k];
                    acc[nt] = __builtin_amdgcn_mfma_f32_16x16x32_bf16(af, bfr, acc[nt], 0, 0, 0);
                }
            }
        }

        float rr[4];
#pragma unroll
        for (int r = 0; r < 4; ++r) {
            int q = qb + wid * 16 + quad * 4 + r;
            float rs = 0.f;
#pragma unroll
            for (int t = 0; t < 8; ++t) rs += rowpart[(size_t)t * 2048 + b * 512 + q];
            rr[r] = 1.0f / rs;
        }
#pragma unroll
        for (int nt = 0; nt < 4; ++nt)
#pragma unroll
            for (int r = 0; r < 4; ++r) {
                int q = qb + wid * 16 + quad * 4 + r;
                out_[((size_t)b * 512 + q) * 512 + nb + nt * 16 + ml] = acc[nt][r] * rr[r];
            }
    }
}

extern "C" void kernel_launch(void* const* d_in, const int* in_sizes, int n_in,
                              void* d_out, int out_size, void* d_ws, size_t ws_size,
                              hipStream_t stream) {
    const float* query = (const float*)d_in[0];
    const float* key   = (const float*)d_in[1];
    const float* value = (const float*)d_in[2];
    const float* wq    = (const float*)d_in[3];
    const float* bq    = (const float*)d_in[4];
    const float* wk    = (const float*)d_in[5];
    const float* bk    = (const float*)d_in[6];
    const float* wv    = (const float*)d_in[7];
    // d_in[8] = bv: row-constant -> softmax-invariant, dropped.
    float* out = (float*)d_out;
    char* ws = (char*)d_ws;

    float c2 = 2.0f * LOG2E;

    void* args[] = {
        (void*)&query, (void*)&key, (void*)&value,
        (void*)&wq, (void*)&wk, (void*)&bq, (void*)&bk, (void*)&wv,
        (void*)&ws, (void*)&out, (void*)&c2
    };
    hipLaunchCooperativeKernel((const void*)fused_kernel,
                               dim3(256), dim3(256), args, 0, stream);
}